// Round 14
// baseline (192.653 us; speedup 1.0000x reference)
//
#include <hip/hip_runtime.h>
#include <math.h>

// Problem constants (from reference)
#define NBLK   4      // NB: blocks
#define NH     8      // H: heads
#define BATCH  2      // B
#define SEQ    1024   // S
#define DIM    512    // D
#define HIDDEN 512    // HID
#define MODF   1.55f  // MOD
#define INV_SQRT_HID 0.04419417382415922f  // 1/sqrt(512)

typedef __bf16 bf16;
typedef __bf16 bf16x4 __attribute__((ext_vector_type(4)));
typedef __bf16 bf16x8 __attribute__((ext_vector_type(8)));
typedef float  floatx4 __attribute__((ext_vector_type(4)));

constexpr int BM = 128, BN = 128, BK = 32;

__device__ __forceinline__ void load16_lds(const bf16* g, bf16* l) {
    __builtin_amdgcn_global_load_lds(
        (__attribute__((address_space(1))) void*)g,
        (__attribute__((address_space(3))) void*)l, 16, 0, 0);
}

// ================= 4-wave core (PROVEN R9, 256 thr): wave = 64x64 ==========
__device__ __forceinline__ void stage32(
    const bf16* __restrict__ Ab, int lda,
    const bf16* __restrict__ Bb, int ldb, int k0,
    bf16* As, bf16* Bs, int w, int l)
{
    const int s0 = 2 * w, s1 = s0 + 1;
    const int r0 = s0 * 16 + (l >> 2);
    const int r1 = s1 * 16 + (l >> 2);
    const int kc = (l & 3) * 8;
    load16_lds(Ab + (size_t)r0 * lda + k0 + kc, As + s0 * 512);
    load16_lds(Ab + (size_t)r1 * lda + k0 + kc, As + s1 * 512);
    load16_lds(Bb + (size_t)r0 * ldb + k0 + kc, Bs + s0 * 512);
    load16_lds(Bb + (size_t)r1 * ldb + k0 + kc, Bs + s1 * 512);
}

__device__ __forceinline__ void comp32(
    const bf16* As, const bf16* Bs,
    int wr, int wc, int fr, int fk, floatx4 (&acc)[4][4])
{
    bf16x8 af[4], bg[4];
#pragma unroll
    for (int i = 0; i < 4; ++i)
        af[i] = *(const bf16x8*)&As[(wr + i * 16 + fr) * BK + fk];
#pragma unroll
    for (int j = 0; j < 4; ++j)
        bg[j] = *(const bf16x8*)&Bs[(wc + j * 16 + fr) * BK + fk];
#pragma unroll
    for (int i = 0; i < 4; ++i)
#pragma unroll
        for (int j = 0; j < 4; ++j)
            acc[i][j] = __builtin_amdgcn_mfma_f32_16x16x32_bf16(
                af[i], bg[j], acc[i][j], 0, 0, 0);
}

__device__ __forceinline__ void mfma_nt4(
    const bf16* __restrict__ A, int lda,
    const bf16* __restrict__ B, int ldb,
    int K, int m0, int n0, floatx4 (&acc)[4][4])
{
    __shared__ __align__(16) bf16 As0[BM * BK];
    __shared__ __align__(16) bf16 Bs0[BN * BK];
    __shared__ __align__(16) bf16 As1[BM * BK];
    __shared__ __align__(16) bf16 Bs1[BN * BK];

    const int tid = threadIdx.x;
    const int l   = tid & 63;
    const int w   = tid >> 6;
    const int wr  = (w >> 1) * 64;
    const int wc  = (w & 1) * 64;
    const int fr  = l & 15;
    const int fk  = (l >> 4) * 8;

    const bf16* Ab = A + (size_t)m0 * lda;
    const bf16* Bb = B + (size_t)n0 * ldb;

    const int nIter = K / BK;
    stage32(Ab, lda, Bb, ldb, 0, As0, Bs0, w, l);
    for (int k = 0; k < nIter; k += 2) {
        __syncthreads();
        if (k + 1 < nIter)
            stage32(Ab, lda, Bb, ldb, (k + 1) * BK, As1, Bs1, w, l);
        comp32(As0, Bs0, wr, wc, fr, fk, acc);
        __syncthreads();
        if (k + 2 < nIter)
            stage32(Ab, lda, Bb, ldb, (k + 2) * BK, As0, Bs0, w, l);
        comp32(As1, Bs1, wr, wc, fr, fk, acc);
    }
}

// ============ 8-wave full-tile core (PROVEN R11, 512 thr): 128x128 =========
__device__ __forceinline__ void stage8(
    const bf16* __restrict__ Ab, int lda,
    const bf16* __restrict__ Bb, int ldb, int k0,
    bf16* As, bf16* Bs, int w, int l)
{
    const int row = w * 16 + (l >> 2);
    const int kc  = (l & 3) * 8;
    load16_lds(Ab + (size_t)row * lda + k0 + kc, As + w * 512);
    load16_lds(Bb + (size_t)row * ldb + k0 + kc, Bs + w * 512);
}

__device__ __forceinline__ void comp8(
    const bf16* As, const bf16* Bs,
    int wr, int wc, int fr, int fk, floatx4 (&acc)[4][2])
{
    bf16x8 af[4], bg[2];
#pragma unroll
    for (int i = 0; i < 4; ++i)
        af[i] = *(const bf16x8*)&As[(wr + i * 16 + fr) * BK + fk];
#pragma unroll
    for (int j = 0; j < 2; ++j)
        bg[j] = *(const bf16x8*)&Bs[(wc + j * 16 + fr) * BK + fk];
#pragma unroll
    for (int i = 0; i < 4; ++i)
#pragma unroll
        for (int j = 0; j < 2; ++j)
            acc[i][j] = __builtin_amdgcn_mfma_f32_16x16x32_bf16(
                af[i], bg[j], acc[i][j], 0, 0, 0);
}

__device__ __forceinline__ void mfma_nt8(
    const bf16* __restrict__ A, int lda,
    const bf16* __restrict__ B, int ldb,
    int K, int m0, int n0, floatx4 (&acc)[4][2])
{
    __shared__ __align__(16) bf16 As0[BM * BK];
    __shared__ __align__(16) bf16 Bs0[BN * BK];
    __shared__ __align__(16) bf16 As1[BM * BK];
    __shared__ __align__(16) bf16 Bs1[BN * BK];

    const int tid = threadIdx.x;
    const int l   = tid & 63;
    const int w   = tid >> 6;            // 0..7
    const int wr  = (w >> 2) * 64;
    const int wc  = (w & 3) * 32;
    const int fr  = l & 15;
    const int fk  = (l >> 4) * 8;

    const bf16* Ab = A + (size_t)m0 * lda;
    const bf16* Bb = B + (size_t)n0 * ldb;

    const int nIter = K / BK;
    stage8(Ab, lda, Bb, ldb, 0, As0, Bs0, w, l);
    for (int k = 0; k < nIter; k += 2) {
        __syncthreads();
        if (k + 1 < nIter)
            stage8(Ab, lda, Bb, ldb, (k + 1) * BK, As1, Bs1, w, l);
        comp8(As0, Bs0, wr, wc, fr, fk, acc);
        __syncthreads();
        if (k + 2 < nIter)
            stage8(Ab, lda, Bb, ldb, (k + 2) * BK, As0, Bs0, w, l);
        comp8(As1, Bs1, wr, wc, fr, fk, acc);
    }
}

// ---------------------------------------------------------------------------
// Merged prep (PROVEN R12): z<16 -> weight transpose slice; z==16 -> xconv.
// ---------------------------------------------------------------------------
__global__ __launch_bounds__(256) void prep_kernel(
    const float* __restrict__ x,
    const float* __restrict__ Wq, const float* __restrict__ Wk,
    const float* __restrict__ Wv, const float* __restrict__ Wo,
    bf16* __restrict__ xb,
    bf16* __restrict__ WqT, bf16* __restrict__ WkT,
    bf16* __restrict__ WvT, bf16* __restrict__ WoT)
{
    const int z = blockIdx.z;
    if (z == 16) {
        const int bid = blockIdx.y * 16 + blockIdx.x;
        const int base = bid * 1024 + threadIdx.x;
#pragma unroll
        for (int i = 0; i < 4; ++i) {
            const int idx = base + i * 256;
            const float4 v = ((const float4*)x)[idx];
            bf16x4 o = { (bf16)v.x, (bf16)v.y, (bf16)v.z, (bf16)v.w };
            *(bf16x4*)&xb[(size_t)idx * 4] = o;
        }
        return;
    }
    __shared__ float tile[32][33];
    const int mat = z >> 2, n = z & 3;
    const float* src; bf16* dst;
    if (mat == 0)      { src = Wq; dst = WqT; }
    else if (mat == 1) { src = Wk; dst = WkT; }
    else if (mat == 2) { src = Wv; dst = WvT; }
    else               { src = Wo; dst = WoT; }
    src += (size_t)n * 512 * 512;
    dst += (size_t)n * 512 * 512;

    const int tx = threadIdx.x & 31, ty = threadIdx.x >> 5;   // 32 x 8
    const int x0 = blockIdx.x * 32, y0 = blockIdx.y * 32;
#pragma unroll
    for (int r = 0; r < 4; ++r)
        tile[ty + r * 8][tx] = src[(size_t)(y0 + ty + r * 8) * 512 + x0 + tx];
    __syncthreads();
#pragma unroll
    for (int r = 0; r < 4; ++r)
        dst[(size_t)(x0 + ty + r * 8) * 512 + y0 + tx] = (bf16)tile[tx][ty + r * 8];
}

// ---------------------------------------------------------------------------
// PROVEN (R9): QKV projections via 4-wave core.  z = which*4 + n.
// which 0 -> Qh [m][h], 1 -> Kh [m][h], 2 -> Vt TRANSPOSED [n*B+b][d][t].
// ---------------------------------------------------------------------------
__global__ __launch_bounds__(256) void proj_mfma_kernel(
    const bf16* __restrict__ xb,
    const bf16* __restrict__ WqT, const bf16* __restrict__ WkT,
    const bf16* __restrict__ WvT,
    const float* __restrict__ bq, const float* __restrict__ bk,
    const float* __restrict__ bv,
    bf16* __restrict__ Qh, bf16* __restrict__ Kh, bf16* __restrict__ Vt)
{
    const int z = blockIdx.z;
    const int n = z & 3, which = z >> 2;
    const bf16* WT; const float* bias;
    if (which == 0)      { WT = WqT; bias = bq; }
    else if (which == 1) { WT = WkT; bias = bk; }
    else                 { WT = WvT; bias = bv; }
    WT   += (size_t)n * DIM * HIDDEN;
    bias += (size_t)n * HIDDEN;

    const int m0 = blockIdx.y * BM, n0 = blockIdx.x * BN;
    floatx4 acc[4][4] = {};
    mfma_nt4(xb, DIM, WT, DIM, DIM, m0, n0, acc);

    const int l = threadIdx.x & 63, w = threadIdx.x >> 6;
    const int rb = m0 + (w >> 1) * 64 + (l >> 4) * 4;
    const int cb = n0 + (w & 1) * 64 + (l & 15);

    if (which != 2) {
        bf16* C = (which ? Kh : Qh) + (size_t)n * (BATCH * SEQ) * HIDDEN;
#pragma unroll
        for (int j = 0; j < 4; ++j) {
            const int col = cb + j * 16;
            const float bc = bias[col];
#pragma unroll
            for (int i = 0; i < 4; ++i)
#pragma unroll
                for (int r = 0; r < 4; ++r)
                    C[(size_t)(rb + i * 16 + r) * HIDDEN + col] = (bf16)(acc[i][j][r] + bc);
        }
    } else {
        const int b = m0 >> 10;
        bf16* Cv = Vt + (size_t)(n * BATCH + b) * HIDDEN * SEQ;
        const int tb = rb & (SEQ - 1);
#pragma unroll
        for (int j = 0; j < 4; ++j) {
            const int col = cb + j * 16;
            const float bc = bias[col];
#pragma unroll
            for (int i = 0; i < 4; ++i) {
                bf16x4 o = { (bf16)(acc[i][j][0] + bc), (bf16)(acc[i][j][1] + bc),
                             (bf16)(acc[i][j][2] + bc), (bf16)(acc[i][j][3] + bc) };
                *(bf16x4*)&Cv[(size_t)col * SEQ + tb + i * 16] = o;
            }
        }
    }
}

// ---------------------------------------------------------------------------
// PROVEN (R11): scores via 8-wave core: P[z][s][t] = (Q.K) / sqrt(HID)
// ---------------------------------------------------------------------------
__global__ __launch_bounds__(512) void scores_mfma_kernel(
    const bf16* __restrict__ Qh, const bf16* __restrict__ Kh,
    float* __restrict__ P)
{
    const int z = blockIdx.z;
    const bf16* A = Qh + (size_t)z * SEQ * HIDDEN;
    const bf16* B = Kh + (size_t)z * SEQ * HIDDEN;
    float* C = P + (size_t)z * SEQ * SEQ;

    const int m0 = blockIdx.y * BM, n0 = blockIdx.x * BN;
    floatx4 acc[4][2] = {};
    mfma_nt8(A, HIDDEN, B, HIDDEN, HIDDEN, m0, n0, acc);

    const int l = threadIdx.x & 63, w = threadIdx.x >> 6;
    const int rb = m0 + (w >> 2) * 64 + (l >> 4) * 4;
    const int cb = n0 + (w & 3) * 32 + (l & 15);
#pragma unroll
    for (int i = 0; i < 4; ++i)
#pragma unroll
        for (int j = 0; j < 2; ++j)
#pragma unroll
            for (int r = 0; r < 4; ++r)
                C[(size_t)(rb + i * 16 + r) * SEQ + cb + j * 16] =
                    acc[i][j][r] * INV_SQRT_HID;
}

// ---------------------------------------------------------------------------
// softmax-combine (head-skip, PROVEN R13) + out-init tail blocks.
// blocks >= 8192: out[m][o] = MOD * sum_n bo[n][o]  (atomics add the rest).
// ---------------------------------------------------------------------------
__global__ __launch_bounds__(256) void softmax_combine_kernel(
    const float* __restrict__ P, bf16* __restrict__ Pb,
    const float* __restrict__ strength, const float* __restrict__ gate,
    const float* __restrict__ bo, float* __restrict__ out)
{
    const int row = blockIdx.x;
    if (row >= NBLK * BATCH * SEQ) {
        // out-init: 256 blocks x 256 thr x 16 elems = 2048*512
        const int b = row - NBLK * BATCH * SEQ;
        const int base = b * 4096 + threadIdx.x * 16;   // elem idx, 16/thread
        const int c = base & (DIM - 1);                 // col of first elem
#pragma unroll
        for (int q = 0; q < 4; ++q) {
            const int cc = c + q * 4;
            float4 bs = make_float4(0.f, 0.f, 0.f, 0.f);
#pragma unroll
            for (int n = 0; n < NBLK; ++n) {
                const float4 bv4 = *(const float4*)(bo + n * DIM + cc);
                bs.x += bv4.x; bs.y += bv4.y; bs.z += bv4.z; bs.w += bv4.w;
            }
            ((float4*)out)[(base >> 2) + q] =
                make_float4(bs.x * MODF, bs.y * MODF, bs.z * MODF, bs.w * MODF);
        }
        return;
    }

    const int n = row >> 11;
    const float* prow = P + (size_t)row * SEQ;
    const int tid = threadIdx.x;
    const int wid = tid >> 6, lane = tid & 63;

    float4 v = ((const float4*)prow)[tid];

    float m = fmaxf(fmaxf(v.x, v.y), fmaxf(v.z, v.w));
#pragma unroll
    for (int off = 32; off > 0; off >>= 1) m = fmaxf(m, __shfl_down(m, off));
    __shared__ float redm[4];
    if (lane == 0) redm[wid] = m;
    __syncthreads();
    const float M = fmaxf(fmaxf(redm[0], redm[1]), fmaxf(redm[2], redm[3]));

    float sh[NH], gh[NH];
#pragma unroll
    for (int h = 0; h < NH; ++h) {
        sh[h] = fminf(fmaxf(strength[n * NH * NH + h * NH + h], 0.01f), 1.0f);
        gh[h] = gate[n * NH + h];      // exactly 0.0 or 1.0, uniform per row
    }

    const float e[4] = { v.x - M, v.y - M, v.z - M, v.w - M };
    float E[4][NH];
    float zsum[NH];
#pragma unroll
    for (int h = 0; h < NH; ++h) zsum[h] = 0.f;
#pragma unroll
    for (int h = 0; h < NH; ++h) {
        if (gh[h] == 0.f) continue;    // wave-uniform skip; skipped terms are 0
#pragma unroll
        for (int i = 0; i < 4; ++i) {
            const float t = __expf(sh[h] * e[i]);
            E[i][h] = t; zsum[h] += t;
        }
    }

    __shared__ float redz[4][NH];
#pragma unroll
    for (int h = 0; h < NH; ++h) {
        if (gh[h] == 0.f) continue;
#pragma unroll
        for (int off = 32; off > 0; off >>= 1) zsum[h] += __shfl_down(zsum[h], off);
        if (lane == 0) redz[wid][h] = zsum[h];
    }
    __syncthreads();

    float wgt[NH];
#pragma unroll
    for (int h = 0; h < NH; ++h) {
        if (gh[h] == 0.f) { wgt[h] = 0.f; continue; }
        const float Z = redz[0][h] + redz[1][h] + redz[2][h] + redz[3][h];
        wgt[h] = gh[h] / Z;
    }

    bf16x4 o;
#pragma unroll
    for (int i = 0; i < 4; ++i) {
        float s = 0.f;
#pragma unroll
        for (int h = 0; h < NH; ++h)
            if (gh[h] != 0.f) s += wgt[h] * E[i][h];
        o[i] = (bf16)s;
    }
    *(bf16x4*)&Pb[(size_t)row * SEQ + tid * 4] = o;
}

// ---------------------------------------------------------------------------
// PROVEN (R11): head_sum via 8-wave core: HS[z][s][d] = Pb[z] @ Vt[z]^T.
// ---------------------------------------------------------------------------
__global__ __launch_bounds__(512) void pv_mfma_kernel(
    const bf16* __restrict__ Pb, const bf16* __restrict__ Vt,
    bf16* __restrict__ HS)
{
    const int z = blockIdx.z;
    const bf16* A = Pb + (size_t)z * SEQ * SEQ;
    const bf16* B = Vt + (size_t)z * HIDDEN * SEQ;
    bf16* C = HS + (size_t)z * SEQ * HIDDEN;

    const int m0 = blockIdx.y * BM, n0 = blockIdx.x * BN;
    floatx4 acc[4][2] = {};
    mfma_nt8(A, SEQ, B, SEQ, SEQ, m0, n0, acc);

    const int l = threadIdx.x & 63, w = threadIdx.x >> 6;
    const int rb = m0 + (w >> 2) * 64 + (l >> 4) * 4;
    const int cb = n0 + (w & 3) * 32 + (l & 15);
#pragma unroll
    for (int i = 0; i < 4; ++i)
#pragma unroll
        for (int j = 0; j < 2; ++j)
#pragma unroll
            for (int r = 0; r < 4; ++r)
                C[(size_t)(rb + i * 16 + r) * HIDDEN + cb + j * 16] =
                    (bf16)acc[i][j][r];
}

// ---------------------------------------------------------------------------
// NEW: out projection with direct atomic accumulation into out.
// out += MOD * (HS[n][m] . WoT[n][o]); init (MOD*bias_sum) done by softmax
// tail blocks. Each address gets exactly NBLK=4 atomic adds -> low contention.
// ---------------------------------------------------------------------------
__global__ __launch_bounds__(512) void out_atomic_kernel(
    const bf16* __restrict__ HS, const bf16* __restrict__ WoT,
    float* __restrict__ out)
{
    const int n = blockIdx.z;
    const bf16* A = HS + (size_t)n * (BATCH * SEQ) * HIDDEN;
    const bf16* B = WoT + (size_t)n * HIDDEN * DIM;

    const int m0 = blockIdx.y * BM, n0 = blockIdx.x * BN;
    floatx4 acc[4][2] = {};
    mfma_nt8(A, HIDDEN, B, HIDDEN, HIDDEN, m0, n0, acc);

    const int l = threadIdx.x & 63, w = threadIdx.x >> 6;
    const int rb = m0 + (w >> 2) * 64 + (l >> 4) * 4;
    const int cb = n0 + (w & 3) * 32 + (l & 15);
#pragma unroll
    for (int i = 0; i < 4; ++i)
#pragma unroll
        for (int j = 0; j < 2; ++j)
#pragma unroll
            for (int r = 0; r < 4; ++r)
                atomicAdd(&out[(size_t)(rb + i * 16 + r) * DIM + cb + j * 16],
                          acc[i][j][r] * MODF);
}

// ---------------------------------------------------------------------------
extern "C" void kernel_launch(void* const* d_in, const int* in_sizes, int n_in,
                              void* d_out, int out_size, void* d_ws, size_t ws_size,
                              hipStream_t stream) {
    const float* x        = (const float*)d_in[0];
    const float* Wq       = (const float*)d_in[1];
    const float* bq       = (const float*)d_in[2];
    const float* Wk       = (const float*)d_in[3];
    const float* bk       = (const float*)d_in[4];
    const float* Wv       = (const float*)d_in[5];
    const float* bv       = (const float*)d_in[6];
    const float* Wo       = (const float*)d_in[7];
    const float* bo       = (const float*)d_in[8];
    const float* strength = (const float*)d_in[9];
    const float* gate     = (const float*)d_in[10];
    float* out = (float*)d_out;

    // workspace (MiB offsets), total 66 MiB:
    //   xb  [0,2) | WqT [2,4) | WkT [4,6) | WvT [6,8) | WoT [8,10)
    //   Qh  [10,18) | Kh [18,26) | Vt bf16 [26,34)
    //   Pf fp32 [34,66)
    //   Pb bf16 (16 MiB) aliases [10,26)  (Qh/Kh dead after scores)
    //   HS bf16 (8 MiB)  aliases [34,42)  (Pf dead after softmax)
    char* ws = (char*)d_ws;
    bf16*  xb    = (bf16*)(ws);
    bf16*  WqT   = (bf16*)(ws + (2u  << 20));
    bf16*  WkT   = (bf16*)(ws + (4u  << 20));
    bf16*  WvT   = (bf16*)(ws + (6u  << 20));
    bf16*  WoT   = (bf16*)(ws + (8u  << 20));
    bf16*  Qh    = (bf16*)(ws + (10u << 20));
    bf16*  Kh    = (bf16*)(ws + (18u << 20));
    bf16*  Vt    = (bf16*)(ws + (26u << 20));
    float* Pf    = (float*)(ws + (34u << 20));
    bf16*  Pb    = (bf16*)(ws + (10u << 20));  // alias over dead Qh/Kh
    bf16*  HS    = (bf16*)(ws + (34u << 20));  // alias over dead Pf (front)

    // prep (merged transpose + xconv): grid (16, 16, 17)
    prep_kernel<<<dim3(16, 16, 17), 256, 0, stream>>>(
        x, Wq, Wk, Wv, Wo, xb, WqT, WkT, WvT, WoT);

    // 1) QKV projections (V stored transposed): grid (4, 16, 12), 256 thr
    proj_mfma_kernel<<<dim3(HIDDEN / BN, (BATCH * SEQ) / BM, 3 * NBLK), 256, 0, stream>>>(
        xb, WqT, WkT, WvT, bq, bk, bv, Qh, Kh, Vt);

    // 2) scores: grid (8, 8, 8), 512 thr
    scores_mfma_kernel<<<dim3(SEQ / BN, SEQ / BM, NBLK * BATCH), 512, 0, stream>>>(
        Qh, Kh, Pf);

    // 3) softmax-combine + out-init: grid 8192 + 256 tail blocks
    softmax_combine_kernel<<<dim3(NBLK * BATCH * SEQ + 256), 256, 0, stream>>>(
        Pf, Pb, strength, gate, bo, out);

    // 4) head_sum: grid (4, 8, 8), 512 thr
    pv_mfma_kernel<<<dim3(HIDDEN / BN, SEQ / BM, NBLK * BATCH), 512, 0, stream>>>(
        Pb, Vt, HS);

    // 5) out projection, atomic accumulate: grid (4, 16, 4), 512 thr
    out_atomic_kernel<<<dim3(DIM / BN, (BATCH * SEQ) / BM, NBLK), 512, 0, stream>>>(
        HS, WoT, out);
}

// Round 15
// 181.574 us; speedup vs baseline: 1.0610x; 1.0610x over previous
//
#include <hip/hip_runtime.h>
#include <math.h>

// Problem constants (from reference)
#define NBLK   4      // NB: blocks
#define NH     8      // H: heads
#define BATCH  2      // B
#define SEQ    1024   // S
#define DIM    512    // D
#define HIDDEN 512    // HID
#define MODF   1.55f  // MOD
#define INV_SQRT_HID 0.04419417382415922f  // 1/sqrt(512)

typedef __bf16 bf16;
typedef __bf16 bf16x4 __attribute__((ext_vector_type(4)));
typedef __bf16 bf16x8 __attribute__((ext_vector_type(8)));
typedef float  floatx4 __attribute__((ext_vector_type(4)));

constexpr int BM = 128, BN = 128, BK = 32;

__device__ __forceinline__ void load16_lds(const bf16* g, bf16* l) {
    __builtin_amdgcn_global_load_lds(
        (__attribute__((address_space(1))) void*)g,
        (__attribute__((address_space(3))) void*)l, 16, 0, 0);
}

// ================= 4-wave core (PROVEN R9, 256 thr): wave = 64x64 ==========
__device__ __forceinline__ void stage32(
    const bf16* __restrict__ Ab, int lda,
    const bf16* __restrict__ Bb, int ldb, int k0,
    bf16* As, bf16* Bs, int w, int l)
{
    const int s0 = 2 * w, s1 = s0 + 1;
    const int r0 = s0 * 16 + (l >> 2);
    const int r1 = s1 * 16 + (l >> 2);
    const int kc = (l & 3) * 8;
    load16_lds(Ab + (size_t)r0 * lda + k0 + kc, As + s0 * 512);
    load16_lds(Ab + (size_t)r1 * lda + k0 + kc, As + s1 * 512);
    load16_lds(Bb + (size_t)r0 * ldb + k0 + kc, Bs + s0 * 512);
    load16_lds(Bb + (size_t)r1 * ldb + k0 + kc, Bs + s1 * 512);
}

__device__ __forceinline__ void comp32(
    const bf16* As, const bf16* Bs,
    int wr, int wc, int fr, int fk, floatx4 (&acc)[4][4])
{
    bf16x8 af[4], bg[4];
#pragma unroll
    for (int i = 0; i < 4; ++i)
        af[i] = *(const bf16x8*)&As[(wr + i * 16 + fr) * BK + fk];
#pragma unroll
    for (int j = 0; j < 4; ++j)
        bg[j] = *(const bf16x8*)&Bs[(wc + j * 16 + fr) * BK + fk];
#pragma unroll
    for (int i = 0; i < 4; ++i)
#pragma unroll
        for (int j = 0; j < 4; ++j)
            acc[i][j] = __builtin_amdgcn_mfma_f32_16x16x32_bf16(
                af[i], bg[j], acc[i][j], 0, 0, 0);
}

__device__ __forceinline__ void mfma_nt4(
    const bf16* __restrict__ A, int lda,
    const bf16* __restrict__ B, int ldb,
    int K, int m0, int n0, floatx4 (&acc)[4][4])
{
    __shared__ __align__(16) bf16 As0[BM * BK];
    __shared__ __align__(16) bf16 Bs0[BN * BK];
    __shared__ __align__(16) bf16 As1[BM * BK];
    __shared__ __align__(16) bf16 Bs1[BN * BK];

    const int tid = threadIdx.x;
    const int l   = tid & 63;
    const int w   = tid >> 6;
    const int wr  = (w >> 1) * 64;
    const int wc  = (w & 1) * 64;
    const int fr  = l & 15;
    const int fk  = (l >> 4) * 8;

    const bf16* Ab = A + (size_t)m0 * lda;
    const bf16* Bb = B + (size_t)n0 * ldb;

    const int nIter = K / BK;
    stage32(Ab, lda, Bb, ldb, 0, As0, Bs0, w, l);
    for (int k = 0; k < nIter; k += 2) {
        __syncthreads();
        if (k + 1 < nIter)
            stage32(Ab, lda, Bb, ldb, (k + 1) * BK, As1, Bs1, w, l);
        comp32(As0, Bs0, wr, wc, fr, fk, acc);
        __syncthreads();
        if (k + 2 < nIter)
            stage32(Ab, lda, Bb, ldb, (k + 2) * BK, As0, Bs0, w, l);
        comp32(As1, Bs1, wr, wc, fr, fk, acc);
    }
}

// ============ 8-wave full-tile core (PROVEN R11, 512 thr): 128x128 =========
__device__ __forceinline__ void stage8(
    const bf16* __restrict__ Ab, int lda,
    const bf16* __restrict__ Bb, int ldb, int k0,
    bf16* As, bf16* Bs, int w, int l)
{
    const int row = w * 16 + (l >> 2);
    const int kc  = (l & 3) * 8;
    load16_lds(Ab + (size_t)row * lda + k0 + kc, As + w * 512);
    load16_lds(Bb + (size_t)row * ldb + k0 + kc, Bs + w * 512);
}

__device__ __forceinline__ void comp8(
    const bf16* As, const bf16* Bs,
    int wr, int wc, int fr, int fk, floatx4 (&acc)[4][2])
{
    bf16x8 af[4], bg[2];
#pragma unroll
    for (int i = 0; i < 4; ++i)
        af[i] = *(const bf16x8*)&As[(wr + i * 16 + fr) * BK + fk];
#pragma unroll
    for (int j = 0; j < 2; ++j)
        bg[j] = *(const bf16x8*)&Bs[(wc + j * 16 + fr) * BK + fk];
#pragma unroll
    for (int i = 0; i < 4; ++i)
#pragma unroll
        for (int j = 0; j < 2; ++j)
            acc[i][j] = __builtin_amdgcn_mfma_f32_16x16x32_bf16(
                af[i], bg[j], acc[i][j], 0, 0, 0);
}

__device__ __forceinline__ void mfma_nt8(
    const bf16* __restrict__ A, int lda,
    const bf16* __restrict__ B, int ldb,
    int K, int m0, int n0, floatx4 (&acc)[4][2])
{
    __shared__ __align__(16) bf16 As0[BM * BK];
    __shared__ __align__(16) bf16 Bs0[BN * BK];
    __shared__ __align__(16) bf16 As1[BM * BK];
    __shared__ __align__(16) bf16 Bs1[BN * BK];

    const int tid = threadIdx.x;
    const int l   = tid & 63;
    const int w   = tid >> 6;            // 0..7
    const int wr  = (w >> 2) * 64;
    const int wc  = (w & 3) * 32;
    const int fr  = l & 15;
    const int fk  = (l >> 4) * 8;

    const bf16* Ab = A + (size_t)m0 * lda;
    const bf16* Bb = B + (size_t)n0 * ldb;

    const int nIter = K / BK;
    stage8(Ab, lda, Bb, ldb, 0, As0, Bs0, w, l);
    for (int k = 0; k < nIter; k += 2) {
        __syncthreads();
        if (k + 1 < nIter)
            stage8(Ab, lda, Bb, ldb, (k + 1) * BK, As1, Bs1, w, l);
        comp8(As0, Bs0, wr, wc, fr, fk, acc);
        __syncthreads();
        if (k + 2 < nIter)
            stage8(Ab, lda, Bb, ldb, (k + 2) * BK, As0, Bs0, w, l);
        comp8(As1, Bs1, wr, wc, fr, fk, acc);
    }
}

// ---------------------------------------------------------------------------
// Merged prep (PROVEN R12): z<16 -> weight transpose slice; z==16 -> xconv.
// ---------------------------------------------------------------------------
__global__ __launch_bounds__(256) void prep_kernel(
    const float* __restrict__ x,
    const float* __restrict__ Wq, const float* __restrict__ Wk,
    const float* __restrict__ Wv, const float* __restrict__ Wo,
    bf16* __restrict__ xb,
    bf16* __restrict__ WqT, bf16* __restrict__ WkT,
    bf16* __restrict__ WvT, bf16* __restrict__ WoT)
{
    const int z = blockIdx.z;
    if (z == 16) {
        const int bid = blockIdx.y * 16 + blockIdx.x;
        const int base = bid * 1024 + threadIdx.x;
#pragma unroll
        for (int i = 0; i < 4; ++i) {
            const int idx = base + i * 256;
            const float4 v = ((const float4*)x)[idx];
            bf16x4 o = { (bf16)v.x, (bf16)v.y, (bf16)v.z, (bf16)v.w };
            *(bf16x4*)&xb[(size_t)idx * 4] = o;
        }
        return;
    }
    __shared__ float tile[32][33];
    const int mat = z >> 2, n = z & 3;
    const float* src; bf16* dst;
    if (mat == 0)      { src = Wq; dst = WqT; }
    else if (mat == 1) { src = Wk; dst = WkT; }
    else if (mat == 2) { src = Wv; dst = WvT; }
    else               { src = Wo; dst = WoT; }
    src += (size_t)n * 512 * 512;
    dst += (size_t)n * 512 * 512;

    const int tx = threadIdx.x & 31, ty = threadIdx.x >> 5;   // 32 x 8
    const int x0 = blockIdx.x * 32, y0 = blockIdx.y * 32;
#pragma unroll
    for (int r = 0; r < 4; ++r)
        tile[ty + r * 8][tx] = src[(size_t)(y0 + ty + r * 8) * 512 + x0 + tx];
    __syncthreads();
#pragma unroll
    for (int r = 0; r < 4; ++r)
        dst[(size_t)(x0 + ty + r * 8) * 512 + y0 + tx] = (bf16)tile[tx][ty + r * 8];
}

// ---------------------------------------------------------------------------
// PROVEN (R9): QKV projections via 4-wave core.  z = which*4 + n.
// which 0 -> Qh [m][h], 1 -> Kh [m][h], 2 -> Vt TRANSPOSED [n*B+b][d][t].
// ---------------------------------------------------------------------------
__global__ __launch_bounds__(256) void proj_mfma_kernel(
    const bf16* __restrict__ xb,
    const bf16* __restrict__ WqT, const bf16* __restrict__ WkT,
    const bf16* __restrict__ WvT,
    const float* __restrict__ bq, const float* __restrict__ bk,
    const float* __restrict__ bv,
    bf16* __restrict__ Qh, bf16* __restrict__ Kh, bf16* __restrict__ Vt)
{
    const int z = blockIdx.z;
    const int n = z & 3, which = z >> 2;
    const bf16* WT; const float* bias;
    if (which == 0)      { WT = WqT; bias = bq; }
    else if (which == 1) { WT = WkT; bias = bk; }
    else                 { WT = WvT; bias = bv; }
    WT   += (size_t)n * DIM * HIDDEN;
    bias += (size_t)n * HIDDEN;

    const int m0 = blockIdx.y * BM, n0 = blockIdx.x * BN;
    floatx4 acc[4][4] = {};
    mfma_nt4(xb, DIM, WT, DIM, DIM, m0, n0, acc);

    const int l = threadIdx.x & 63, w = threadIdx.x >> 6;
    const int rb = m0 + (w >> 1) * 64 + (l >> 4) * 4;
    const int cb = n0 + (w & 1) * 64 + (l & 15);

    if (which != 2) {
        bf16* C = (which ? Kh : Qh) + (size_t)n * (BATCH * SEQ) * HIDDEN;
#pragma unroll
        for (int j = 0; j < 4; ++j) {
            const int col = cb + j * 16;
            const float bc = bias[col];
#pragma unroll
            for (int i = 0; i < 4; ++i)
#pragma unroll
                for (int r = 0; r < 4; ++r)
                    C[(size_t)(rb + i * 16 + r) * HIDDEN + col] = (bf16)(acc[i][j][r] + bc);
        }
    } else {
        const int b = m0 >> 10;
        bf16* Cv = Vt + (size_t)(n * BATCH + b) * HIDDEN * SEQ;
        const int tb = rb & (SEQ - 1);
#pragma unroll
        for (int j = 0; j < 4; ++j) {
            const int col = cb + j * 16;
            const float bc = bias[col];
#pragma unroll
            for (int i = 0; i < 4; ++i) {
                bf16x4 o = { (bf16)(acc[i][j][0] + bc), (bf16)(acc[i][j][1] + bc),
                             (bf16)(acc[i][j][2] + bc), (bf16)(acc[i][j][3] + bc) };
                *(bf16x4*)&Cv[(size_t)col * SEQ + tb + i * 16] = o;
            }
        }
    }
}

// ---------------------------------------------------------------------------
// PROVEN (R11): scores via 8-wave core: P[z][s][t] = (Q.K) / sqrt(HID)
// ---------------------------------------------------------------------------
__global__ __launch_bounds__(512) void scores_mfma_kernel(
    const bf16* __restrict__ Qh, const bf16* __restrict__ Kh,
    float* __restrict__ P)
{
    const int z = blockIdx.z;
    const bf16* A = Qh + (size_t)z * SEQ * HIDDEN;
    const bf16* B = Kh + (size_t)z * SEQ * HIDDEN;
    float* C = P + (size_t)z * SEQ * SEQ;

    const int m0 = blockIdx.y * BM, n0 = blockIdx.x * BN;
    floatx4 acc[4][2] = {};
    mfma_nt8(A, HIDDEN, B, HIDDEN, HIDDEN, m0, n0, acc);

    const int l = threadIdx.x & 63, w = threadIdx.x >> 6;
    const int rb = m0 + (w >> 2) * 64 + (l >> 4) * 4;
    const int cb = n0 + (w & 3) * 32 + (l & 15);
#pragma unroll
    for (int i = 0; i < 4; ++i)
#pragma unroll
        for (int j = 0; j < 2; ++j)
#pragma unroll
            for (int r = 0; r < 4; ++r)
                C[(size_t)(rb + i * 16 + r) * SEQ + cb + j * 16] =
                    acc[i][j][r] * INV_SQRT_HID;
}

// ---------------------------------------------------------------------------
// NEW softmax-combine: ONE ROW PER WAVE, 4 rows/block, grid 2048.
// All reductions are in-wave shuffles (no LDS/barriers). E recomputed in
// pass 2 (exp cost ~3.5us chip-wide, below memory floor). Head-skip kept.
// ---------------------------------------------------------------------------
__global__ __launch_bounds__(256) void softmax_combine_kernel(
    const float* __restrict__ P, bf16* __restrict__ Pb,
    const float* __restrict__ strength, const float* __restrict__ gate)
{
    const int row  = blockIdx.x * 4 + (threadIdx.x >> 6);  // wave -> row
    const int lane = threadIdx.x & 63;
    const int n = row >> 11;
    const float* prow = P + (size_t)row * SEQ;

    // load 16 elems/lane as 4 coalesced float4s: float4 index c*64+lane
    float4 v[4];
#pragma unroll
    for (int c = 0; c < 4; ++c) v[c] = ((const float4*)prow)[c * 64 + lane];

    // row max: local over 16, then 64-lane butterfly
    float m = -1e30f;
#pragma unroll
    for (int c = 0; c < 4; ++c)
        m = fmaxf(m, fmaxf(fmaxf(v[c].x, v[c].y), fmaxf(v[c].z, v[c].w)));
#pragma unroll
    for (int off = 32; off > 0; off >>= 1) m = fmaxf(m, __shfl_xor(m, off));
    const float M = m;

    float sh[NH], gh[NH];
#pragma unroll
    for (int h = 0; h < NH; ++h) {
        sh[h] = fminf(fmaxf(strength[n * NH * NH + h * NH + h], 0.01f), 1.0f);
        gh[h] = gate[n * NH + h];      // exactly 0.0 or 1.0, uniform per row
    }

    // pass 1: per-active-head exp-sums (E recomputed later)
    float zsum[NH];
#pragma unroll
    for (int h = 0; h < NH; ++h) zsum[h] = 0.f;
#pragma unroll
    for (int h = 0; h < NH; ++h) {
        if (gh[h] == 0.f) continue;
        float s = 0.f;
#pragma unroll
        for (int c = 0; c < 4; ++c) {
            s += __expf(sh[h] * (v[c].x - M));
            s += __expf(sh[h] * (v[c].y - M));
            s += __expf(sh[h] * (v[c].z - M));
            s += __expf(sh[h] * (v[c].w - M));
        }
        zsum[h] = s;
    }
    float wgt[NH];
#pragma unroll
    for (int h = 0; h < NH; ++h) {
        if (gh[h] == 0.f) { wgt[h] = 0.f; continue; }
        float Z = zsum[h];
#pragma unroll
        for (int off = 32; off > 0; off >>= 1) Z += __shfl_xor(Z, off);
        wgt[h] = gh[h] / Z;
    }

    // pass 2: combined probabilities, bf16 out
    bf16* prowb = Pb + (size_t)row * SEQ;
#pragma unroll
    for (int c = 0; c < 4; ++c) {
        float o0 = 0.f, o1 = 0.f, o2 = 0.f, o3 = 0.f;
#pragma unroll
        for (int h = 0; h < NH; ++h) {
            if (gh[h] == 0.f) continue;
            o0 += wgt[h] * __expf(sh[h] * (v[c].x - M));
            o1 += wgt[h] * __expf(sh[h] * (v[c].y - M));
            o2 += wgt[h] * __expf(sh[h] * (v[c].z - M));
            o3 += wgt[h] * __expf(sh[h] * (v[c].w - M));
        }
        bf16x4 o = { (bf16)o0, (bf16)o1, (bf16)o2, (bf16)o3 };
        *(bf16x4*)&prowb[(c * 64 + lane) * 4] = o;
    }
}

// ---------------------------------------------------------------------------
// PROVEN (R11): head_sum via 8-wave core: HS[z][s][d] = Pb[z] @ Vt[z]^T.
// ---------------------------------------------------------------------------
__global__ __launch_bounds__(512) void pv_mfma_kernel(
    const bf16* __restrict__ Pb, const bf16* __restrict__ Vt,
    bf16* __restrict__ HS)
{
    const int z = blockIdx.z;
    const bf16* A = Pb + (size_t)z * SEQ * SEQ;
    const bf16* B = Vt + (size_t)z * HIDDEN * SEQ;
    bf16* C = HS + (size_t)z * SEQ * HIDDEN;

    const int m0 = blockIdx.y * BM, n0 = blockIdx.x * BN;
    floatx4 acc[4][2] = {};
    mfma_nt8(A, SEQ, B, SEQ, SEQ, m0, n0, acc);

    const int l = threadIdx.x & 63, w = threadIdx.x >> 6;
    const int rb = m0 + (w >> 2) * 64 + (l >> 4) * 4;
    const int cb = n0 + (w & 3) * 32 + (l & 15);
#pragma unroll
    for (int i = 0; i < 4; ++i)
#pragma unroll
        for (int j = 0; j < 2; ++j)
#pragma unroll
            for (int r = 0; r < 4; ++r)
                C[(size_t)(rb + i * 16 + r) * HIDDEN + cb + j * 16] =
                    (bf16)acc[i][j][r];
}

// ---------------------------------------------------------------------------
// PROVEN (R11): out projection partials via 8-wave core, n in blockIdx.z.
// ---------------------------------------------------------------------------
__global__ __launch_bounds__(512) void out_partial_kernel(
    const bf16* __restrict__ HS, const bf16* __restrict__ WoT,
    float* __restrict__ Opart)
{
    const int n = blockIdx.z;
    const bf16* A = HS + (size_t)n * (BATCH * SEQ) * HIDDEN;
    const bf16* B = WoT + (size_t)n * HIDDEN * DIM;
    float* C = Opart + (size_t)n * (BATCH * SEQ) * DIM;

    const int m0 = blockIdx.y * BM, n0 = blockIdx.x * BN;
    floatx4 acc[4][2] = {};
    mfma_nt8(A, HIDDEN, B, HIDDEN, HIDDEN, m0, n0, acc);

    const int l = threadIdx.x & 63, w = threadIdx.x >> 6;
    const int rb = m0 + (w >> 2) * 64 + (l >> 4) * 4;
    const int cb = n0 + (w & 3) * 32 + (l & 15);
#pragma unroll
    for (int i = 0; i < 4; ++i)
#pragma unroll
        for (int j = 0; j < 2; ++j)
#pragma unroll
            for (int r = 0; r < 4; ++r)
                C[(size_t)(rb + i * 16 + r) * DIM + cb + j * 16] = acc[i][j][r];
}

// ---------------------------------------------------------------------------
// PROVEN: reduce 4 partials + bias + MOD.
// ---------------------------------------------------------------------------
__global__ __launch_bounds__(256) void out_reduce_kernel(
    const float* __restrict__ Opart, const float* __restrict__ bo,
    float* __restrict__ out)
{
    const size_t t = (size_t)blockIdx.x * 256 + threadIdx.x;   // float4 index
    const int c = (int)((t * 4) & (DIM - 1));                  // col of .x
    const size_t stride4 = (size_t)(BATCH * SEQ) * DIM / 4;

    float4 s = ((const float4*)Opart)[t];
#pragma unroll
    for (int n = 1; n < NBLK; ++n) {
        const float4 p = ((const float4*)Opart)[t + n * stride4];
        s.x += p.x; s.y += p.y; s.z += p.z; s.w += p.w;
    }
    float4 bs = make_float4(0.f, 0.f, 0.f, 0.f);
#pragma unroll
    for (int n = 0; n < NBLK; ++n) {
        const float4 b = *(const float4*)(bo + n * DIM + c);
        bs.x += b.x; bs.y += b.y; bs.z += b.z; bs.w += b.w;
    }
    ((float4*)out)[t] = make_float4((s.x + bs.x) * MODF, (s.y + bs.y) * MODF,
                                    (s.z + bs.z) * MODF, (s.w + bs.w) * MODF);
}

// ---------------------------------------------------------------------------
extern "C" void kernel_launch(void* const* d_in, const int* in_sizes, int n_in,
                              void* d_out, int out_size, void* d_ws, size_t ws_size,
                              hipStream_t stream) {
    const float* x        = (const float*)d_in[0];
    const float* Wq       = (const float*)d_in[1];
    const float* bq       = (const float*)d_in[2];
    const float* Wk       = (const float*)d_in[3];
    const float* bk       = (const float*)d_in[4];
    const float* Wv       = (const float*)d_in[5];
    const float* bv       = (const float*)d_in[6];
    const float* Wo       = (const float*)d_in[7];
    const float* bo       = (const float*)d_in[8];
    const float* strength = (const float*)d_in[9];
    const float* gate     = (const float*)d_in[10];
    float* out = (float*)d_out;

    // workspace (MiB offsets), total 66 MiB:
    //   xb  [0,2) | WqT [2,4) | WkT [4,6) | WvT [6,8) | WoT [8,10)
    //   Qh  [10,18) | Kh [18,26) | Vt bf16 [26,34)
    //   Pf fp32 [34,66)
    //   Pb bf16 (16 MiB)    aliases [10,26)  (Qh/Kh dead after scores)
    //   HS bf16 (8 MiB)     aliases [34,42)  (Pf dead after softmax)
    //   Opart fp32 (16 MiB) aliases [42,58)  (rest of dead Pf)
    char* ws = (char*)d_ws;
    bf16*  xb    = (bf16*)(ws);
    bf16*  WqT   = (bf16*)(ws + (2u  << 20));
    bf16*  WkT   = (bf16*)(ws + (4u  << 20));
    bf16*  WvT   = (bf16*)(ws + (6u  << 20));
    bf16*  WoT   = (bf16*)(ws + (8u  << 20));
    bf16*  Qh    = (bf16*)(ws + (10u << 20));
    bf16*  Kh    = (bf16*)(ws + (18u << 20));
    bf16*  Vt    = (bf16*)(ws + (26u << 20));
    float* Pf    = (float*)(ws + (34u << 20));
    bf16*  Pb    = (bf16*)(ws + (10u << 20));  // alias over dead Qh/Kh
    bf16*  HS    = (bf16*)(ws + (34u << 20));  // alias over dead Pf (front)
    float* Opart = (float*)(ws + (42u << 20)); // alias over dead Pf (rest)

    // prep (merged transpose + xconv): grid (16, 16, 17)
    prep_kernel<<<dim3(16, 16, 17), 256, 0, stream>>>(
        x, Wq, Wk, Wv, Wo, xb, WqT, WkT, WvT, WoT);

    // 1) QKV projections (V stored transposed): grid (4, 16, 12), 256 thr
    proj_mfma_kernel<<<dim3(HIDDEN / BN, (BATCH * SEQ) / BM, 3 * NBLK), 256, 0, stream>>>(
        xb, WqT, WkT, WvT, bq, bk, bv, Qh, Kh, Vt);

    // 2) scores: grid (8, 8, 8), 512 thr
    scores_mfma_kernel<<<dim3(SEQ / BN, SEQ / BM, NBLK * BATCH), 512, 0, stream>>>(
        Qh, Kh, Pf);

    // 3) softmax-combine: 1 row/wave, 4 rows/block -> grid 2048
    softmax_combine_kernel<<<dim3(NBLK * BATCH * SEQ / 4), 256, 0, stream>>>(
        Pf, Pb, strength, gate);

    // 4) head_sum: grid (4, 8, 8), 512 thr
    pv_mfma_kernel<<<dim3(HIDDEN / BN, SEQ / BM, NBLK * BATCH), 512, 0, stream>>>(
        Pb, Vt, HS);

    // 5) out projection partials: grid (4, 16, 4), 512 thr
    out_partial_kernel<<<dim3(DIM / BN, (BATCH * SEQ) / BM, NBLK), 512, 0, stream>>>(
        HS, WoT, Opart);

    // 5b) reduce + bias + MOD
    out_reduce_kernel<<<dim3((BATCH * SEQ) * DIM / 4 / 256), 256, 0, stream>>>(
        Opart, bo, out);
}

// Round 16
// 176.619 us; speedup vs baseline: 1.0908x; 1.0281x over previous
//
#include <hip/hip_runtime.h>
#include <math.h>

// Problem constants (from reference)
#define NBLK   4      // NB: blocks
#define NH     8      // H: heads
#define BATCH  2      // B
#define SEQ    1024   // S
#define DIM    512    // D
#define HIDDEN 512    // HID
#define MODF   1.55f  // MOD
#define INV_SQRT_HID 0.04419417382415922f  // 1/sqrt(512)

typedef __bf16 bf16;
typedef __bf16 bf16x4 __attribute__((ext_vector_type(4)));
typedef __bf16 bf16x8 __attribute__((ext_vector_type(8)));
typedef float  floatx4 __attribute__((ext_vector_type(4)));

constexpr int BM = 128, BN = 128, BK = 32;

__device__ __forceinline__ void load16_lds(const bf16* g, bf16* l) {
    __builtin_amdgcn_global_load_lds(
        (__attribute__((address_space(1))) void*)g,
        (__attribute__((address_space(3))) void*)l, 16, 0, 0);
}

// ============ 8-wave full-tile core (PROVEN R11, 512 thr): 128x128 =========
__device__ __forceinline__ void stage8(
    const bf16* __restrict__ Ab, int lda,
    const bf16* __restrict__ Bb, int ldb, int k0,
    bf16* As, bf16* Bs, int w, int l)
{
    const int row = w * 16 + (l >> 2);
    const int kc  = (l & 3) * 8;
    load16_lds(Ab + (size_t)row * lda + k0 + kc, As + w * 512);
    load16_lds(Bb + (size_t)row * ldb + k0 + kc, Bs + w * 512);
}

__device__ __forceinline__ void comp8(
    const bf16* As, const bf16* Bs,
    int wr, int wc, int fr, int fk, floatx4 (&acc)[4][2])
{
    bf16x8 af[4], bg[2];
#pragma unroll
    for (int i = 0; i < 4; ++i)
        af[i] = *(const bf16x8*)&As[(wr + i * 16 + fr) * BK + fk];
#pragma unroll
    for (int j = 0; j < 2; ++j)
        bg[j] = *(const bf16x8*)&Bs[(wc + j * 16 + fr) * BK + fk];
#pragma unroll
    for (int i = 0; i < 4; ++i)
#pragma unroll
        for (int j = 0; j < 2; ++j)
            acc[i][j] = __builtin_amdgcn_mfma_f32_16x16x32_bf16(
                af[i], bg[j], acc[i][j], 0, 0, 0);
}

__device__ __forceinline__ void mfma_nt8(
    const bf16* __restrict__ A, int lda,
    const bf16* __restrict__ B, int ldb,
    int K, int m0, int n0, floatx4 (&acc)[4][2])
{
    __shared__ __align__(16) bf16 As0[BM * BK];
    __shared__ __align__(16) bf16 Bs0[BN * BK];
    __shared__ __align__(16) bf16 As1[BM * BK];
    __shared__ __align__(16) bf16 Bs1[BN * BK];

    const int tid = threadIdx.x;
    const int l   = tid & 63;
    const int w   = tid >> 6;            // 0..7
    const int wr  = (w >> 2) * 64;
    const int wc  = (w & 3) * 32;
    const int fr  = l & 15;
    const int fk  = (l >> 4) * 8;

    const bf16* Ab = A + (size_t)m0 * lda;
    const bf16* Bb = B + (size_t)n0 * ldb;

    const int nIter = K / BK;
    stage8(Ab, lda, Bb, ldb, 0, As0, Bs0, w, l);
    for (int k = 0; k < nIter; k += 2) {
        __syncthreads();
        if (k + 1 < nIter)
            stage8(Ab, lda, Bb, ldb, (k + 1) * BK, As1, Bs1, w, l);
        comp8(As0, Bs0, wr, wc, fr, fk, acc);
        __syncthreads();
        if (k + 2 < nIter)
            stage8(Ab, lda, Bb, ldb, (k + 2) * BK, As0, Bs0, w, l);
        comp8(As1, Bs1, wr, wc, fr, fk, acc);
    }
}

// ---------------------------------------------------------------------------
// Merged prep (PROVEN R12): z<16 -> weight transpose slice; z==16 -> xconv.
// ---------------------------------------------------------------------------
__global__ __launch_bounds__(256) void prep_kernel(
    const float* __restrict__ x,
    const float* __restrict__ Wq, const float* __restrict__ Wk,
    const float* __restrict__ Wv, const float* __restrict__ Wo,
    bf16* __restrict__ xb,
    bf16* __restrict__ WqT, bf16* __restrict__ WkT,
    bf16* __restrict__ WvT, bf16* __restrict__ WoT)
{
    const int z = blockIdx.z;
    if (z == 16) {
        const int bid = blockIdx.y * 16 + blockIdx.x;
        const int base = bid * 1024 + threadIdx.x;
#pragma unroll
        for (int i = 0; i < 4; ++i) {
            const int idx = base + i * 256;
            const float4 v = ((const float4*)x)[idx];
            bf16x4 o = { (bf16)v.x, (bf16)v.y, (bf16)v.z, (bf16)v.w };
            *(bf16x4*)&xb[(size_t)idx * 4] = o;
        }
        return;
    }
    __shared__ float tile[32][33];
    const int mat = z >> 2, n = z & 3;
    const float* src; bf16* dst;
    if (mat == 0)      { src = Wq; dst = WqT; }
    else if (mat == 1) { src = Wk; dst = WkT; }
    else if (mat == 2) { src = Wv; dst = WvT; }
    else               { src = Wo; dst = WoT; }
    src += (size_t)n * 512 * 512;
    dst += (size_t)n * 512 * 512;

    const int tx = threadIdx.x & 31, ty = threadIdx.x >> 5;   // 32 x 8
    const int x0 = blockIdx.x * 32, y0 = blockIdx.y * 32;
#pragma unroll
    for (int r = 0; r < 4; ++r)
        tile[ty + r * 8][tx] = src[(size_t)(y0 + ty + r * 8) * 512 + x0 + tx];
    __syncthreads();
#pragma unroll
    for (int r = 0; r < 4; ++r)
        dst[(size_t)(x0 + ty + r * 8) * 512 + y0 + tx] = (bf16)tile[tx][ty + r * 8];
}

// ---------------------------------------------------------------------------
// QKV projections via 8-wave core (NEW config; math/order unchanged).
// z = which*4 + n.  which 0 -> Qh [m][h], 1 -> Kh [m][h],
// which 2 -> Vt TRANSPOSED [n*B+b][d][t].
// ---------------------------------------------------------------------------
__global__ __launch_bounds__(512) void proj_mfma_kernel(
    const bf16* __restrict__ xb,
    const bf16* __restrict__ WqT, const bf16* __restrict__ WkT,
    const bf16* __restrict__ WvT,
    const float* __restrict__ bq, const float* __restrict__ bk,
    const float* __restrict__ bv,
    bf16* __restrict__ Qh, bf16* __restrict__ Kh, bf16* __restrict__ Vt)
{
    const int z = blockIdx.z;
    const int n = z & 3, which = z >> 2;
    const bf16* WT; const float* bias;
    if (which == 0)      { WT = WqT; bias = bq; }
    else if (which == 1) { WT = WkT; bias = bk; }
    else                 { WT = WvT; bias = bv; }
    WT   += (size_t)n * DIM * HIDDEN;
    bias += (size_t)n * HIDDEN;

    const int m0 = blockIdx.y * BM, n0 = blockIdx.x * BN;
    floatx4 acc[4][2] = {};
    mfma_nt8(xb, DIM, WT, DIM, DIM, m0, n0, acc);

    const int l = threadIdx.x & 63, w = threadIdx.x >> 6;
    const int rb = m0 + (w >> 2) * 64 + (l >> 4) * 4;
    const int cb = n0 + (w & 3) * 32 + (l & 15);

    if (which != 2) {
        bf16* C = (which ? Kh : Qh) + (size_t)n * (BATCH * SEQ) * HIDDEN;
#pragma unroll
        for (int j = 0; j < 2; ++j) {
            const int col = cb + j * 16;
            const float bc = bias[col];
#pragma unroll
            for (int i = 0; i < 4; ++i)
#pragma unroll
                for (int r = 0; r < 4; ++r)
                    C[(size_t)(rb + i * 16 + r) * HIDDEN + col] = (bf16)(acc[i][j][r] + bc);
        }
    } else {
        // transposed store: row m = b*SEQ + s -> Vt[n*B+b][d=col][t=s]
        const int b = m0 >> 10;                       // BM=128 tile never crosses
        bf16* Cv = Vt + (size_t)(n * BATCH + b) * HIDDEN * SEQ;
        const int tb = rb & (SEQ - 1);
#pragma unroll
        for (int j = 0; j < 2; ++j) {
            const int col = cb + j * 16;
            const float bc = bias[col];
#pragma unroll
            for (int i = 0; i < 4; ++i) {
                bf16x4 o = { (bf16)(acc[i][j][0] + bc), (bf16)(acc[i][j][1] + bc),
                             (bf16)(acc[i][j][2] + bc), (bf16)(acc[i][j][3] + bc) };
                *(bf16x4*)&Cv[(size_t)col * SEQ + tb + i * 16] = o;
            }
        }
    }
}

// ---------------------------------------------------------------------------
// PROVEN (R11): scores via 8-wave core: P[z][s][t] = (Q.K) / sqrt(HID)
// ---------------------------------------------------------------------------
__global__ __launch_bounds__(512) void scores_mfma_kernel(
    const bf16* __restrict__ Qh, const bf16* __restrict__ Kh,
    float* __restrict__ P)
{
    const int z = blockIdx.z;
    const bf16* A = Qh + (size_t)z * SEQ * HIDDEN;
    const bf16* B = Kh + (size_t)z * SEQ * HIDDEN;
    float* C = P + (size_t)z * SEQ * SEQ;

    const int m0 = blockIdx.y * BM, n0 = blockIdx.x * BN;
    floatx4 acc[4][2] = {};
    mfma_nt8(A, HIDDEN, B, HIDDEN, HIDDEN, m0, n0, acc);

    const int l = threadIdx.x & 63, w = threadIdx.x >> 6;
    const int rb = m0 + (w >> 2) * 64 + (l >> 4) * 4;
    const int cb = n0 + (w & 3) * 32 + (l & 15);
#pragma unroll
    for (int i = 0; i < 4; ++i)
#pragma unroll
        for (int j = 0; j < 2; ++j)
#pragma unroll
            for (int r = 0; r < 4; ++r)
                C[(size_t)(rb + i * 16 + r) * SEQ + cb + j * 16] =
                    acc[i][j][r] * INV_SQRT_HID;
}

// ---------------------------------------------------------------------------
// PROVEN (R15): softmax-combine, one row per wave, 4 rows/block, grid 2048.
// ---------------------------------------------------------------------------
__global__ __launch_bounds__(256) void softmax_combine_kernel(
    const float* __restrict__ P, bf16* __restrict__ Pb,
    const float* __restrict__ strength, const float* __restrict__ gate)
{
    const int row  = blockIdx.x * 4 + (threadIdx.x >> 6);  // wave -> row
    const int lane = threadIdx.x & 63;
    const int n = row >> 11;
    const float* prow = P + (size_t)row * SEQ;

    float4 v[4];
#pragma unroll
    for (int c = 0; c < 4; ++c) v[c] = ((const float4*)prow)[c * 64 + lane];

    float m = -1e30f;
#pragma unroll
    for (int c = 0; c < 4; ++c)
        m = fmaxf(m, fmaxf(fmaxf(v[c].x, v[c].y), fmaxf(v[c].z, v[c].w)));
#pragma unroll
    for (int off = 32; off > 0; off >>= 1) m = fmaxf(m, __shfl_xor(m, off));
    const float M = m;

    float sh[NH], gh[NH];
#pragma unroll
    for (int h = 0; h < NH; ++h) {
        sh[h] = fminf(fmaxf(strength[n * NH * NH + h * NH + h], 0.01f), 1.0f);
        gh[h] = gate[n * NH + h];      // exactly 0.0 or 1.0, uniform per row
    }

    float zsum[NH];
#pragma unroll
    for (int h = 0; h < NH; ++h) zsum[h] = 0.f;
#pragma unroll
    for (int h = 0; h < NH; ++h) {
        if (gh[h] == 0.f) continue;
        float s = 0.f;
#pragma unroll
        for (int c = 0; c < 4; ++c) {
            s += __expf(sh[h] * (v[c].x - M));
            s += __expf(sh[h] * (v[c].y - M));
            s += __expf(sh[h] * (v[c].z - M));
            s += __expf(sh[h] * (v[c].w - M));
        }
        zsum[h] = s;
    }
    float wgt[NH];
#pragma unroll
    for (int h = 0; h < NH; ++h) {
        if (gh[h] == 0.f) { wgt[h] = 0.f; continue; }
        float Z = zsum[h];
#pragma unroll
        for (int off = 32; off > 0; off >>= 1) Z += __shfl_xor(Z, off);
        wgt[h] = gh[h] / Z;
    }

    bf16* prowb = Pb + (size_t)row * SEQ;
#pragma unroll
    for (int c = 0; c < 4; ++c) {
        float o0 = 0.f, o1 = 0.f, o2 = 0.f, o3 = 0.f;
#pragma unroll
        for (int h = 0; h < NH; ++h) {
            if (gh[h] == 0.f) continue;
            o0 += wgt[h] * __expf(sh[h] * (v[c].x - M));
            o1 += wgt[h] * __expf(sh[h] * (v[c].y - M));
            o2 += wgt[h] * __expf(sh[h] * (v[c].z - M));
            o3 += wgt[h] * __expf(sh[h] * (v[c].w - M));
        }
        bf16x4 o = { (bf16)o0, (bf16)o1, (bf16)o2, (bf16)o3 };
        *(bf16x4*)&prowb[(c * 64 + lane) * 4] = o;
    }
}

// ---------------------------------------------------------------------------
// PROVEN (R11): head_sum via 8-wave core: HS[z][s][d] = Pb[z] @ Vt[z]^T.
// ---------------------------------------------------------------------------
__global__ __launch_bounds__(512) void pv_mfma_kernel(
    const bf16* __restrict__ Pb, const bf16* __restrict__ Vt,
    bf16* __restrict__ HS)
{
    const int z = blockIdx.z;
    const bf16* A = Pb + (size_t)z * SEQ * SEQ;
    const bf16* B = Vt + (size_t)z * HIDDEN * SEQ;
    bf16* C = HS + (size_t)z * SEQ * HIDDEN;

    const int m0 = blockIdx.y * BM, n0 = blockIdx.x * BN;
    floatx4 acc[4][2] = {};
    mfma_nt8(A, SEQ, B, SEQ, SEQ, m0, n0, acc);

    const int l = threadIdx.x & 63, w = threadIdx.x >> 6;
    const int rb = m0 + (w >> 2) * 64 + (l >> 4) * 4;
    const int cb = n0 + (w & 3) * 32 + (l & 15);
#pragma unroll
    for (int i = 0; i < 4; ++i)
#pragma unroll
        for (int j = 0; j < 2; ++j)
#pragma unroll
            for (int r = 0; r < 4; ++r)
                C[(size_t)(rb + i * 16 + r) * HIDDEN + cb + j * 16] =
                    (bf16)acc[i][j][r];
}

// ---------------------------------------------------------------------------
// PROVEN (R11): out projection partials via 8-wave core, n in blockIdx.z.
// ---------------------------------------------------------------------------
__global__ __launch_bounds__(512) void out_partial_kernel(
    const bf16* __restrict__ HS, const bf16* __restrict__ WoT,
    float* __restrict__ Opart)
{
    const int n = blockIdx.z;
    const bf16* A = HS + (size_t)n * (BATCH * SEQ) * HIDDEN;
    const bf16* B = WoT + (size_t)n * HIDDEN * DIM;
    float* C = Opart + (size_t)n * (BATCH * SEQ) * DIM;

    const int m0 = blockIdx.y * BM, n0 = blockIdx.x * BN;
    floatx4 acc[4][2] = {};
    mfma_nt8(A, HIDDEN, B, HIDDEN, HIDDEN, m0, n0, acc);

    const int l = threadIdx.x & 63, w = threadIdx.x >> 6;
    const int rb = m0 + (w >> 2) * 64 + (l >> 4) * 4;
    const int cb = n0 + (w & 3) * 32 + (l & 15);
#pragma unroll
    for (int i = 0; i < 4; ++i)
#pragma unroll
        for (int j = 0; j < 2; ++j)
#pragma unroll
            for (int r = 0; r < 4; ++r)
                C[(size_t)(rb + i * 16 + r) * DIM + cb + j * 16] = acc[i][j][r];
}

// ---------------------------------------------------------------------------
// PROVEN: reduce 4 partials + bias + MOD.
// ---------------------------------------------------------------------------
__global__ __launch_bounds__(256) void out_reduce_kernel(
    const float* __restrict__ Opart, const float* __restrict__ bo,
    float* __restrict__ out)
{
    const size_t t = (size_t)blockIdx.x * 256 + threadIdx.x;   // float4 index
    const int c = (int)((t * 4) & (DIM - 1));                  // col of .x
    const size_t stride4 = (size_t)(BATCH * SEQ) * DIM / 4;

    float4 s = ((const float4*)Opart)[t];
#pragma unroll
    for (int n = 1; n < NBLK; ++n) {
        const float4 p = ((const float4*)Opart)[t + n * stride4];
        s.x += p.x; s.y += p.y; s.z += p.z; s.w += p.w;
    }
    float4 bs = make_float4(0.f, 0.f, 0.f, 0.f);
#pragma unroll
    for (int n = 0; n < NBLK; ++n) {
        const float4 b = *(const float4*)(bo + n * DIM + c);
        bs.x += b.x; bs.y += b.y; bs.z += b.z; bs.w += b.w;
    }
    ((float4*)out)[t] = make_float4((s.x + bs.x) * MODF, (s.y + bs.y) * MODF,
                                    (s.z + bs.z) * MODF, (s.w + bs.w) * MODF);
}

// ---------------------------------------------------------------------------
extern "C" void kernel_launch(void* const* d_in, const int* in_sizes, int n_in,
                              void* d_out, int out_size, void* d_ws, size_t ws_size,
                              hipStream_t stream) {
    const float* x        = (const float*)d_in[0];
    const float* Wq       = (const float*)d_in[1];
    const float* bq       = (const float*)d_in[2];
    const float* Wk       = (const float*)d_in[3];
    const float* bk       = (const float*)d_in[4];
    const float* Wv       = (const float*)d_in[5];
    const float* bv       = (const float*)d_in[6];
    const float* Wo       = (const float*)d_in[7];
    const float* bo       = (const float*)d_in[8];
    const float* strength = (const float*)d_in[9];
    const float* gate     = (const float*)d_in[10];
    float* out = (float*)d_out;

    // workspace (MiB offsets), total 66 MiB:
    //   xb  [0,2) | WqT [2,4) | WkT [4,6) | WvT [6,8) | WoT [8,10)
    //   Qh  [10,18) | Kh [18,26) | Vt bf16 [26,34)
    //   Pf fp32 [34,66)
    //   Pb bf16 (16 MiB)    aliases [10,26)  (Qh/Kh dead after scores)
    //   HS bf16 (8 MiB)     aliases [34,42)  (Pf dead after softmax)
    //   Opart fp32 (16 MiB) aliases [42,58)  (rest of dead Pf)
    char* ws = (char*)d_ws;
    bf16*  xb    = (bf16*)(ws);
    bf16*  WqT   = (bf16*)(ws + (2u  << 20));
    bf16*  WkT   = (bf16*)(ws + (4u  << 20));
    bf16*  WvT   = (bf16*)(ws + (6u  << 20));
    bf16*  WoT   = (bf16*)(ws + (8u  << 20));
    bf16*  Qh    = (bf16*)(ws + (10u << 20));
    bf16*  Kh    = (bf16*)(ws + (18u << 20));
    bf16*  Vt    = (bf16*)(ws + (26u << 20));
    float* Pf    = (float*)(ws + (34u << 20));
    bf16*  Pb    = (bf16*)(ws + (10u << 20));  // alias over dead Qh/Kh
    bf16*  HS    = (bf16*)(ws + (34u << 20));  // alias over dead Pf (front)
    float* Opart = (float*)(ws + (42u << 20)); // alias over dead Pf (rest)

    // prep (merged transpose + xconv): grid (16, 16, 17)
    prep_kernel<<<dim3(16, 16, 17), 256, 0, stream>>>(
        x, Wq, Wk, Wv, Wo, xb, WqT, WkT, WvT, WoT);

    // 1) QKV projections (V stored transposed): grid (4, 16, 12), 512 thr
    proj_mfma_kernel<<<dim3(HIDDEN / BN, (BATCH * SEQ) / BM, 3 * NBLK), 512, 0, stream>>>(
        xb, WqT, WkT, WvT, bq, bk, bv, Qh, Kh, Vt);

    // 2) scores: grid (8, 8, 8), 512 thr
    scores_mfma_kernel<<<dim3(SEQ / BN, SEQ / BM, NBLK * BATCH), 512, 0, stream>>>(
        Qh, Kh, Pf);

    // 3) softmax-combine: 1 row/wave, 4 rows/block -> grid 2048
    softmax_combine_kernel<<<dim3(NBLK * BATCH * SEQ / 4), 256, 0, stream>>>(
        Pf, Pb, strength, gate);

    // 4) head_sum: grid (4, 8, 8), 512 thr
    pv_mfma_kernel<<<dim3(HIDDEN / BN, SEQ / BM, NBLK * BATCH), 512, 0, stream>>>(
        Pb, Vt, HS);

    // 5) out projection partials: grid (4, 16, 4), 512 thr
    out_partial_kernel<<<dim3(DIM / BN, (BATCH * SEQ) / BM, NBLK), 512, 0, stream>>>(
        HS, WoT, Opart);

    // 5b) reduce + bias + MOD
    out_reduce_kernel<<<dim3((BATCH * SEQ) * DIM / 4 / 256), 256, 0, stream>>>(
        Opart, bo, out);
}